// Round 9
// baseline (206.897 us; speedup 1.0000x reference)
//
#include <hip/hip_runtime.h>
#include <hip/hip_bf16.h>

// Problem constants (from reference)
#define BB   16
#define VV   5
#define NPTS 8192
#define CCH  128
#define HH   41
#define WW   32
#define HWS  (HH * WW)      // 1312
#define BVN  (BB * VV)      // 80
#define OUTC (3 + CCH)      // 131

typedef unsigned int u32;

static __device__ __forceinline__ u32 pack2bf(float a, float b) {
    __hip_bfloat16 ha = __float2bfloat16(a);   // RNE
    __hip_bfloat16 hb = __float2bfloat16(b);
    ushort ua = *reinterpret_cast<ushort*>(&ha);
    ushort ub = *reinterpret_cast<ushort*>(&hb);
    return (u32)ua | ((u32)ub << 16);
}
static __device__ __forceinline__ float bf2f(u32 lo16) {
    return __uint_as_float(lo16 << 16);
}

// ---------------------------------------------------------------------------
// K1: winner resolution, one block per bv, entirely in LDS.
// numpy fancy-assignment = last i wins; key = (i<<11)|src (24 bits), init -1.
// ---------------------------------------------------------------------------
__global__ void win_resolve(const int* __restrict__ i3, const int* __restrict__ i2,
                            int* __restrict__ win) {
    __shared__ int smem[NPTS];                  // 32 KB
    int tid = threadIdx.x;                      // 256
    int bv  = blockIdx.x;
    const int* p3 = i3 + (size_t)bv * (NPTS + 1);
    const int* p2 = i2 + (size_t)bv * (NPTS + 1);
    for (int j = tid; j < NPTS; j += 256) smem[j] = -1;
    __syncthreads();
    int cnt = p3[0];
    for (int i = tid; i < cnt; i += 256) {
        int tgt = p3[1 + i];                    // [0, NPTS)
        int src = p2[1 + i];                    // [0, HWS)
        atomicMax(&smem[tgt], (i << 11) | src);
    }
    __syncthreads();
    int4* wg = (int4*)(win + (size_t)bv * NPTS);
    const int4* s4 = (const int4*)smem;
    for (int j = tid; j < NPTS / 4; j += 256) wg[j] = s4[j];
}

// ---------------------------------------------------------------------------
// K2: fused stage+gather. Block = (b, c8): 8-channel slice of one batch.
// Grid g = c8*16 + b  ->  XCD = g%8 = b%8: all 16 blocks of a batch share one
// XCD's L2 (win reuse + out cache-line assembly). 256 blocks = 1 per CU.
//
// Per view v: stage feat[b*V+v][c8*8..+8][:] (42 KB f32) as bf16 into LDS
// [hw][8ch] (21 KB, double-buffered); gather per point via ds_read_b128 at
// win-src, unpack, fmax into acc[8][8] f32. Next view's global loads issue
// BEFORE the barrier so HBM latency hides under the gather (T14 pattern).
// Unset view contributes exact 0.0 (NOT a clamp). bf16 only inside LDS:
// threshold 0.104 vs bf16 err <= ~0.01 on N(0,1).
// ---------------------------------------------------------------------------
__global__ __launch_bounds__(1024) void fused_gather(
        const float* __restrict__ pc, const float* __restrict__ feat,
        const int* __restrict__ win, float* __restrict__ out) {
    __shared__ u32 buf[2][HWS][4];              // 2 x 1312 x 16B = 42 KB
    int g   = blockIdx.x;
    int b   = g & 15;
    int c8  = g >> 4;                           // 0..15
    int tid = threadIdx.x;                      // 0..1023

    const int  hw1  = tid;                      // always < 1312
    const int  hw2  = 1024 + tid;
    const bool has2 = (tid < HWS - 1024);       // 288 threads

    // ---- prologue: stage view 0 into buf[0], prefetch view-0 keys
    float s1[8], s2[8];
    {
        const float* f0 = feat + ((size_t)(b * VV + 0) * CCH + c8 * 8) * HWS;
#pragma unroll
        for (int j = 0; j < 8; ++j) s1[j] = f0[(size_t)j * HWS + hw1];
        if (has2) {
#pragma unroll
            for (int j = 0; j < 8; ++j) s2[j] = f0[(size_t)j * HWS + hw2];
        }
        u32* w1 = &buf[0][hw1][0];
        w1[0] = pack2bf(s1[0], s1[1]); w1[1] = pack2bf(s1[2], s1[3]);
        w1[2] = pack2bf(s1[4], s1[5]); w1[3] = pack2bf(s1[6], s1[7]);
        if (has2) {
            u32* w2 = &buf[0][hw2][0];
            w2[0] = pack2bf(s2[0], s2[1]); w2[1] = pack2bf(s2[2], s2[3]);
            w2[2] = pack2bf(s2[4], s2[5]); w2[3] = pack2bf(s2[6], s2[7]);
        }
    }
    int keys[8], keysn[8];
#pragma unroll
    for (int k = 0; k < 8; ++k)
        keys[k] = win[(size_t)(b * VV + 0) * NPTS + k * 1024 + tid];

    float acc[8][8];
#pragma unroll
    for (int k = 0; k < 8; ++k)
#pragma unroll
        for (int j = 0; j < 8; ++j) acc[k][j] = -INFINITY;

    // ---- main loop over views
    for (int v = 0; v < VV; ++v) {
        if (v + 1 < VV) {                       // issue next-view loads early
            const float* fn = feat + ((size_t)(b * VV + v + 1) * CCH + c8 * 8) * HWS;
#pragma unroll
            for (int j = 0; j < 8; ++j) s1[j] = fn[(size_t)j * HWS + hw1];
            if (has2) {
#pragma unroll
                for (int j = 0; j < 8; ++j) s2[j] = fn[(size_t)j * HWS + hw2];
            }
#pragma unroll
            for (int k = 0; k < 8; ++k)
                keysn[k] = win[(size_t)(b * VV + v + 1) * NPTS + k * 1024 + tid];
        }
        __syncthreads();                        // buf[v&1] fully written

        const u32 (*bc)[4] = buf[v & 1];
#pragma unroll
        for (int k = 0; k < 8; ++k) {
            int key = keys[k];
            float val[8];
            if (key >= 0) {
                int src = key & 2047;
                u32 q0 = bc[src][0], q1 = bc[src][1], q2 = bc[src][2], q3 = bc[src][3];
                val[0] = bf2f(q0 & 0xffff); val[1] = bf2f(q0 >> 16);
                val[2] = bf2f(q1 & 0xffff); val[3] = bf2f(q1 >> 16);
                val[4] = bf2f(q2 & 0xffff); val[5] = bf2f(q2 >> 16);
                val[6] = bf2f(q3 & 0xffff); val[7] = bf2f(q3 >> 16);
            } else {
#pragma unroll
                for (int j = 0; j < 8; ++j) val[j] = 0.0f;
            }
#pragma unroll
            for (int j = 0; j < 8; ++j) acc[k][j] = fmaxf(acc[k][j], val[j]);
        }

        if (v + 1 < VV) {                       // write staged regs to other buffer
            // safe: all reads of buf[(v+1)&1] (view v-1) finished before the
            // __syncthreads above.
            u32* w1 = &buf[(v + 1) & 1][hw1][0];
            w1[0] = pack2bf(s1[0], s1[1]); w1[1] = pack2bf(s1[2], s1[3]);
            w1[2] = pack2bf(s1[4], s1[5]); w1[3] = pack2bf(s1[6], s1[7]);
            if (has2) {
                u32* w2 = &buf[(v + 1) & 1][hw2][0];
                w2[0] = pack2bf(s2[0], s2[1]); w2[1] = pack2bf(s2[2], s2[3]);
                w2[2] = pack2bf(s2[4], s2[5]); w2[3] = pack2bf(s2[6], s2[7]);
            }
#pragma unroll
            for (int k = 0; k < 8; ++k) keys[k] = keysn[k];
        }
    }

    // ---- epilogue: write 8-channel slice of each owned point's row (+xyz)
#pragma unroll
    for (int k = 0; k < 8; ++k) {
        int p = k * 1024 + tid;
        float* orow = out + ((size_t)b * NPTS + p) * OUTC;
#pragma unroll
        for (int j = 0; j < 8; ++j) orow[3 + c8 * 8 + j] = acc[k][j];
        if (c8 == 0) {
            const float* pr = pc + ((size_t)b * NPTS + p) * 3;
            orow[0] = pr[0]; orow[1] = pr[1]; orow[2] = pr[2];
        }
    }
}

extern "C" void kernel_launch(void* const* d_in, const int* in_sizes, int n_in,
                              void* d_out, int out_size, void* d_ws, size_t ws_size,
                              hipStream_t stream) {
    const float* pc   = (const float*)d_in[0];
    const float* feat = (const float*)d_in[1];
    const int*   i3   = (const int*)d_in[2];
    const int*   i2   = (const int*)d_in[3];
    float*       out  = (float*)d_out;

    int* win = (int*)d_ws;                      // 2.62 MB
    (void)ws_size;

    win_resolve<<<BVN, 256, 0, stream>>>(i3, i2, win);
    fused_gather<<<BB * 16, 1024, 0, stream>>>(pc, feat, win, out);
}

// Round 10
// 45.103 us; speedup vs baseline: 4.5872x; 4.5872x over previous
//
#include <hip/hip_runtime.h>
#include <hip/hip_bf16.h>

// Problem constants (from reference)
#define BB   16
#define VV   5
#define NPTS 8192
#define CCH  128
#define HH   41
#define WW   32
#define HWS  (HH * WW)      // 1312
#define BVN  (BB * VV)      // 80
#define OUTC (3 + CCH)      // 131
#define PPB  16             // points per block in gather

#define NSCAT BVN                    // 80 scatter blocks (1 per bv)
#define NTRAN (41 * BVN)             // 3280 transpose blocks (128c x 32hw tile)

typedef unsigned int u32;

static __device__ __forceinline__ u32 pack2bf(float a, float b) {
    __hip_bfloat16 ha = __float2bfloat16(a);   // RNE
    __hip_bfloat16 hb = __float2bfloat16(b);
    ushort ua = *reinterpret_cast<ushort*>(&ha);
    ushort ub = *reinterpret_cast<ushort*>(&hb);
    return (u32)ua | ((u32)ub << 16);          // a -> lower address (c ascending)
}
static __device__ __forceinline__ float bf2f(ushort u) {
    return __uint_as_float(((u32)u) << 16);
}

// ---------------------------------------------------------------------------
// Kernel 1 (fused):
//  blocks [0, 80): winner resolution entirely in LDS (32 KB win image per bv,
//    LDS atomicMax, coalesced int4 write-out). numpy fancy-assignment = last
//    i wins; key = (i<<11)|src (24 bits), init -1.
//  blocks [80, 80+3280): transpose feat (BV,C,HW) f32 -> (BV,HW,C) bf16.
//    128c x 32hw tile: 4 independent float4 loads per thread (64 B in
//    flight -- R8's version had only 16 B and was latency-thin), then 2 x
//    16 B uint4 bf16 stores. LDS tile [128][33] aliases the scatter's smem.
//  R7 lesson: non-temporal hints regress (-7%); plain cached accesses.
//  R9 lesson: never split an output row across blocks (write amplification).
// ---------------------------------------------------------------------------
__global__ void scatter_and_transpose(const int* __restrict__ i3, const int* __restrict__ i2,
                                      int* __restrict__ win,
                                      const float* __restrict__ feat,
                                      __hip_bfloat16* __restrict__ feat_t) {
    __shared__ int smem[NPTS];                   // 32 KB; transpose aliases 16.9 KB
    int tid = threadIdx.x;                       // 256

    if (blockIdx.x < NSCAT) {
        int bv = blockIdx.x;
        const int* p3 = i3 + (size_t)bv * (NPTS + 1);
        const int* p2 = i2 + (size_t)bv * (NPTS + 1);
        for (int j = tid; j < NPTS; j += 256) smem[j] = -1;
        __syncthreads();
        int cnt = p3[0];
        for (int i = tid; i < cnt; i += 256) {
            int tgt = p3[1 + i];                 // [0, NPTS)
            int src = p2[1 + i];                 // [0, HWS)
            atomicMax(&smem[tgt], (i << 11) | src);
        }
        __syncthreads();
        int4* wg = (int4*)(win + (size_t)bv * NPTS);
        const int4* s4 = (const int4*)smem;
        for (int j = tid; j < NPTS / 4; j += 256) wg[j] = s4[j];
        return;
    }

    // ---- transpose block: 128c x 32hw tile ----
    float (*tile)[33] = (float (*)[33])smem;     // 128 x 33 floats = 16.9 KB
    int t   = blockIdx.x - NSCAT;                // 0..3279
    int bv  = t / 41;
    int hw0 = (t - bv * 41) * 32;
    const float* inp  = feat + (size_t)bv * CCH * HWS;
    ushort*      outp = (ushort*)feat_t + (size_t)bv * HWS * CCH;

    {   // read phase: ty = c row within 32-group, tx = hw quad; 4 loads in flight
        int ty = tid >> 3, tx = tid & 7;
        float4 r[4];
#pragma unroll
        for (int cb = 0; cb < 4; ++cb)
            r[cb] = *(const float4*)(inp + (size_t)(cb * 32 + ty) * HWS + hw0 + 4 * tx);
#pragma unroll
        for (int cb = 0; cb < 4; ++cb) {
            tile[cb * 32 + ty][4 * tx + 0] = r[cb].x;
            tile[cb * 32 + ty][4 * tx + 1] = r[cb].y;
            tile[cb * 32 + ty][4 * tx + 2] = r[cb].z;
            tile[cb * 32 + ty][4 * tx + 3] = r[cb].w;
        }
    }
    __syncthreads();
    {   // write phase: h = hw row (0..31), oct = 8-channel group; 2 x uint4 stores
        int h = tid >> 3, oc = tid & 7;
#pragma unroll
        for (int ob = 0; ob < 2; ++ob) {
            int oct = ob * 8 + oc;               // 0..15
            u32 w0 = pack2bf(tile[oct * 8 + 0][h], tile[oct * 8 + 1][h]);
            u32 w1 = pack2bf(tile[oct * 8 + 2][h], tile[oct * 8 + 3][h]);
            u32 w2 = pack2bf(tile[oct * 8 + 4][h], tile[oct * 8 + 5][h]);
            u32 w3 = pack2bf(tile[oct * 8 + 6][h], tile[oct * 8 + 7][h]);
            *(uint4*)(outp + (size_t)(hw0 + h) * CCH + oct * 8) = make_uint4(w0, w1, w2, w3);
        }
    }
}

// ---------------------------------------------------------------------------
// Kernel 2: per point, max over views (unset view contributes exact 0.0; NOT
// a clamp -- if all 5 views set, max can be negative). Each lane reads a
// 16B uint4 (8 bf16 channels) per view from (BV,HW,C) bf16; 5 independent
// loads in flight. Output rows staged in LDS, one contiguous coalesced
// 8384 B block write (R9 lesson: rows must not be split across blocks).
// ---------------------------------------------------------------------------
__global__ void gather_out_bf(const float* __restrict__ pc, const ushort* __restrict__ feat_t,
                              const int* __restrict__ win, float* __restrict__ out) {
    __shared__ __align__(16) float srow[PPB * OUTC];   // 16*131 = 2096 floats
    int tid = threadIdx.x;          // 256
    int row = tid >> 4;             // 0..15
    int c8  = tid & 15;             // 8-channel group index
    int bp0 = blockIdx.x * PPB;
    int bp  = bp0 + row;
    int b   = bp >> 13;
    int p   = bp & (NPTS - 1);

    int keys[VV];
#pragma unroll
    for (int v = 0; v < VV; ++v)
        keys[v] = win[(b * VV + v) * NPTS + p];

    float acc[8];
#pragma unroll
    for (int j = 0; j < 8; ++j) acc[j] = -INFINITY;

#pragma unroll
    for (int v = 0; v < VV; ++v) {
        float val[8];
        if (keys[v] >= 0) {
            int src = keys[v] & 2047;
            uint4 q = *(const uint4*)(feat_t + (((size_t)(b * VV + v) * HWS + src) << 7) + (c8 << 3));
            val[0] = bf2f((ushort)(q.x & 0xffff)); val[1] = bf2f((ushort)(q.x >> 16));
            val[2] = bf2f((ushort)(q.y & 0xffff)); val[3] = bf2f((ushort)(q.y >> 16));
            val[4] = bf2f((ushort)(q.z & 0xffff)); val[5] = bf2f((ushort)(q.z >> 16));
            val[6] = bf2f((ushort)(q.w & 0xffff)); val[7] = bf2f((ushort)(q.w >> 16));
        } else {
#pragma unroll
            for (int j = 0; j < 8; ++j) val[j] = 0.0f;
        }
#pragma unroll
        for (int j = 0; j < 8; ++j) acc[j] = fmaxf(acc[j], val[j]);
    }

    float* sr = srow + row * OUTC;
#pragma unroll
    for (int j = 0; j < 8; ++j) sr[3 + 8 * c8 + j] = acc[j];
    if (c8 < 3) sr[c8] = pc[(size_t)bp * 3 + c8];
    __syncthreads();

    // coalesced aligned copy-out: 2096 floats = 524 float4
    float* obase = out + (size_t)bp0 * OUTC;
    const float4* s4 = (const float4*)srow;
    for (int i = tid; i < (PPB * OUTC) / 4; i += 256)
        *(float4*)(obase + 4 * i) = s4[i];
}

extern "C" void kernel_launch(void* const* d_in, const int* in_sizes, int n_in,
                              void* d_out, int out_size, void* d_ws, size_t ws_size,
                              hipStream_t stream) {
    const float* pc   = (const float*)d_in[0];
    const float* feat = (const float*)d_in[1];
    const int*   i3   = (const int*)d_in[2];
    const int*   i2   = (const int*)d_in[3];
    float*       out  = (float*)d_out;

    const size_t win_bytes = (size_t)BVN * NPTS * sizeof(int);   // 2.62 MB

    int* win = (int*)d_ws;
    __hip_bfloat16* feat_t = (__hip_bfloat16*)((char*)d_ws + win_bytes);
    (void)ws_size;

    scatter_and_transpose<<<NSCAT + NTRAN, 256, 0, stream>>>(i3, i2, win, feat, feat_t);
    gather_out_bf<<<(BB * NPTS) / PPB, 256, 0, stream>>>(pc, (const ushort*)feat_t, win, out);
}

// Round 11
// 38.708 us; speedup vs baseline: 5.3451x; 1.1652x over previous
//
#include <hip/hip_runtime.h>
#include <hip/hip_bf16.h>

// Problem constants (from reference)
#define BB   16
#define VV   5
#define NPTS 8192
#define CCH  128
#define HH   41
#define WW   32
#define HWS  (HH * WW)      // 1312
#define BVN  (BB * VV)      // 80
#define OUTC (3 + CCH)      // 131
#define PPB  16             // points per block in gather

#define NSCAT BVN                                // 80 scatter blocks (1 per bv)
#define NTRAN ((HWS / 32) * (CCH / 32) * BVN)    // 41*4*80 = 13120 transpose blocks

typedef unsigned int u32;

static __device__ __forceinline__ ushort f2bf(float x) {
    __hip_bfloat16 h = __float2bfloat16(x);      // RNE
    return *reinterpret_cast<ushort*>(&h);
}
static __device__ __forceinline__ float bf2f(ushort u) {
    return __uint_as_float(((u32)u) << 16);
}

// ---------------------------------------------------------------------------
// Kernel 1 (fused) -- EXACT R8 structure (R10's 128x32 tile regressed +2 us):
//  blocks [0, 80): winner resolution entirely in LDS (32 KB win image per bv,
//    LDS atomicMax, coalesced int4 write-out). numpy fancy-assignment = last
//    i wins; key = (i<<11)|src (24 bits), init -1.
//  blocks [80, 80+13120): transpose feat (BV,C,HW) f32 -> (BV,HW,C) bf16,
//    32x32 tile, float4 in / ushort4 out, LDS stride 37.
//  R7 lesson: non-temporal hints regress (+7%). R9 lesson: never split an
//  output row across blocks. R10 lesson: bigger transpose tile regresses.
// ---------------------------------------------------------------------------
__global__ void scatter_and_transpose(const int* __restrict__ i3, const int* __restrict__ i2,
                                      int* __restrict__ win,
                                      const float* __restrict__ feat,
                                      __hip_bfloat16* __restrict__ feat_t) {
    __shared__ int smem[NPTS];                   // 32 KB, aliased by transpose tile
    int tid = threadIdx.x;                       // 256

    if (blockIdx.x < NSCAT) {
        int bv = blockIdx.x;
        const int* p3 = i3 + (size_t)bv * (NPTS + 1);
        const int* p2 = i2 + (size_t)bv * (NPTS + 1);
        for (int j = tid; j < NPTS; j += 256) smem[j] = -1;
        __syncthreads();
        int cnt = p3[0];
        for (int i = tid; i < cnt; i += 256) {
            int tgt = p3[1 + i];                 // [0, NPTS)
            int src = p2[1 + i];                 // [0, HWS)
            atomicMax(&smem[tgt], (i << 11) | src);
        }
        __syncthreads();
        int4* wg = (int4*)(win + (size_t)bv * NPTS);
        const int4* s4 = (const int4*)smem;
        for (int j = tid; j < NPTS / 4; j += 256) wg[j] = s4[j];
        return;
    }

    // ---- transpose block ----
    float (*tile)[37] = (float (*)[37])smem;
    int t   = blockIdx.x - NSCAT;
    int bv  = t / (41 * 4);
    int rem = t - bv * (41 * 4);
    int hw0 = (rem % 41) * 32;
    int c0  = (rem / 41) * 32;
    const float*    inp  = feat   + (size_t)bv * CCH * HWS;
    __hip_bfloat16* outp = feat_t + (size_t)bv * HWS * CCH;

    {   // read: ty = c row (0..31), tx = hw quad (0..7), float4 along hw
        int ty = tid >> 3, tx = tid & 7;
        float4 v = *(const float4*)(inp + (size_t)(c0 + ty) * HWS + hw0 + 4 * tx);
        tile[ty][4 * tx + 0] = v.x;
        tile[ty][4 * tx + 1] = v.y;
        tile[ty][4 * tx + 2] = v.z;
        tile[ty][4 * tx + 3] = v.w;
    }
    __syncthreads();
    {   // write: h = hw (0..31), q = c quad (0..7), ushort4 (4 bf16 = 8B)
        int h = tid >> 3, q = tid & 7;
        ushort4 v;
        v.x = f2bf(tile[4 * q + 0][h]);
        v.y = f2bf(tile[4 * q + 1][h]);
        v.z = f2bf(tile[4 * q + 2][h]);
        v.w = f2bf(tile[4 * q + 3][h]);
        *(ushort4*)((ushort*)outp + (size_t)(hw0 + h) * CCH + c0 + 4 * q) = v;
    }
}

// ---------------------------------------------------------------------------
// Kernel 2: per point, max over views (unset view contributes exact 0.0; NOT
// a clamp). Each lane reads a 16B uint4 (8 bf16 channels) per view; 5
// independent loads in flight. Output rows staged in LDS, one contiguous
// coalesced 8384 B block write.
//
// NEW (R11): XCD-pinning swizzle. n=blockIdx.x; xcd=n&7; slot=n>>3;
// b = xcd + 8*(slot>>9); j = slot&511  (bijective: 16 batches x 512 blocks).
// All 512 blocks of batch b land on XCD b%8 (round-robin heuristic), so the
// batch's 1.68 MB feat_t slice + 160 KB win stay resident in that XCD's
// 4 MB L2 across the 5x logical reuse.
// ---------------------------------------------------------------------------
__global__ void gather_out_bf(const float* __restrict__ pc, const ushort* __restrict__ feat_t,
                              const int* __restrict__ win, float* __restrict__ out) {
    __shared__ __align__(16) float srow[PPB * OUTC];   // 16*131 = 2096 floats
    int tid  = threadIdx.x;         // 256
    int row  = tid >> 4;            // 0..15
    int c8   = tid & 15;            // 8-channel group index

    int n    = blockIdx.x;          // 0..8191
    int xcd  = n & 7;
    int slot = n >> 3;              // 0..1023
    int b    = xcd + 8 * (slot >> 9);
    int j    = slot & 511;
    int bp0  = (b * 512 + j) * PPB; // batch-local block j, 16 points
    int bp   = bp0 + row;
    int p    = (bp & (NPTS - 1));

    int keys[VV];
#pragma unroll
    for (int v = 0; v < VV; ++v)
        keys[v] = win[(b * VV + v) * NPTS + p];

    float acc[8];
#pragma unroll
    for (int j2 = 0; j2 < 8; ++j2) acc[j2] = -INFINITY;

#pragma unroll
    for (int v = 0; v < VV; ++v) {
        float val[8];
        if (keys[v] >= 0) {
            int src = keys[v] & 2047;
            uint4 q = *(const uint4*)(feat_t + (((size_t)(b * VV + v) * HWS + src) << 7) + (c8 << 3));
            val[0] = bf2f((ushort)(q.x & 0xffff)); val[1] = bf2f((ushort)(q.x >> 16));
            val[2] = bf2f((ushort)(q.y & 0xffff)); val[3] = bf2f((ushort)(q.y >> 16));
            val[4] = bf2f((ushort)(q.z & 0xffff)); val[5] = bf2f((ushort)(q.z >> 16));
            val[6] = bf2f((ushort)(q.w & 0xffff)); val[7] = bf2f((ushort)(q.w >> 16));
        } else {
#pragma unroll
            for (int j2 = 0; j2 < 8; ++j2) val[j2] = 0.0f;
        }
#pragma unroll
        for (int j2 = 0; j2 < 8; ++j2) acc[j2] = fmaxf(acc[j2], val[j2]);
    }

    float* sr = srow + row * OUTC;
#pragma unroll
    for (int j2 = 0; j2 < 8; ++j2) sr[3 + 8 * c8 + j2] = acc[j2];
    if (c8 < 3) sr[c8] = pc[(size_t)bp * 3 + c8];
    __syncthreads();

    // coalesced aligned copy-out: 2096 floats = 524 float4
    float* obase = out + (size_t)bp0 * OUTC;
    const float4* s4 = (const float4*)srow;
    for (int i = tid; i < (PPB * OUTC) / 4; i += 256)
        *(float4*)(obase + 4 * i) = s4[i];
}

extern "C" void kernel_launch(void* const* d_in, const int* in_sizes, int n_in,
                              void* d_out, int out_size, void* d_ws, size_t ws_size,
                              hipStream_t stream) {
    const float* pc   = (const float*)d_in[0];
    const float* feat = (const float*)d_in[1];
    const int*   i3   = (const int*)d_in[2];
    const int*   i2   = (const int*)d_in[3];
    float*       out  = (float*)d_out;

    const size_t win_bytes = (size_t)BVN * NPTS * sizeof(int);   // 2.62 MB

    int* win = (int*)d_ws;
    __hip_bfloat16* feat_t = (__hip_bfloat16*)((char*)d_ws + win_bytes);
    (void)ws_size;

    scatter_and_transpose<<<NSCAT + NTRAN, 256, 0, stream>>>(i3, i2, win, feat, feat_t);
    gather_out_bf<<<(BB * NPTS) / PPB, 256, 0, stream>>>(pc, (const ushort*)feat_t, win, out);
}